// Round 4
// baseline (300.753 us; speedup 1.0000x reference)
//
#include <hip/hip_runtime.h>

typedef __attribute__((ext_vector_type(8))) short short8;
typedef __attribute__((ext_vector_type(4))) float f32x4;

#define GLDS(gp, lp) __builtin_amdgcn_global_load_lds( \
    (const __attribute__((address_space(1))) void*)(gp), \
    (__attribute__((address_space(3))) void*)(lp), 16, 0, 0)

__device__ __forceinline__ unsigned short f2bf(float f){
    unsigned u = __float_as_uint(f);
    unsigned r = (u + 0x7fffu + ((u >> 16) & 1u)) >> 16;
    return (unsigned short)r;
}
__device__ __forceinline__ float bf2f(unsigned short s){
    return __uint_as_float(((unsigned)s) << 16);
}

// ---------------- init: cast weights to bf16 + zero stats ----------------
__global__ __launch_bounds__(256) void init_kernel(const float* __restrict__ W1, const float* __restrict__ W2,
                                                   unsigned short* __restrict__ W1c, unsigned short* __restrict__ W2c,
                                                   float* __restrict__ stats){
    int i = blockIdx.x * 256 + threadIdx.x;
    if (i < 98304) W1c[i] = f2bf(W1[i]);
    if (i < 32768) W2c[i] = f2bf(W2[i]);
    if (i < 768) stats[i] = 0.f;
}

// ---------------- KNN (3-NN), branchless insert ----------------
// grid 1024 = B(8) * 128 blocks; 64 points/block; thread = (pointpair pp, chunk sub):
// handles points {pp, pp+32} against candidates [sub*256, sub*256+256).
__global__ __launch_bounds__(256) void knn_kernel(const float* __restrict__ xyz1, const float* __restrict__ xyz2,
                                                  int* __restrict__ oi, float* __restrict__ ow){
    __shared__ float sx[2048], sy[2048], sz[2048];
    __shared__ float sd[64][25];
    __shared__ int   si[64][25];
    int blk = blockIdx.x;
    int b  = blk >> 7;
    int n0 = (blk & 127) << 6;
    const float* p2 = xyz2 + (size_t)b * 2048 * 3;
    for (int j = threadIdx.x; j < 2048; j += 256){
        sx[j] = p2[j*3+0]; sy[j] = p2[j*3+1]; sz[j] = p2[j*3+2];
    }
    __syncthreads();
    int pp = threadIdx.x & 31, sub = threadIdx.x >> 5;
    int pA = n0 + pp;
    const float* qa = xyz1 + ((size_t)b * 8192 + pA) * 3;
    float ax = qa[0], ay = qa[1], az = qa[2];
    float bx = qa[96], by = qa[97], bz = qa[98];   // point pA+32
    float A0 = 1e30f, A1 = 1e30f, A2 = 1e30f; int Ai0 = 0, Ai1 = 0, Ai2 = 0;
    float B0 = 1e30f, B1 = 1e30f, B2 = 1e30f; int Bi0 = 0, Bi1 = 0, Bi2 = 0;
    int jb = sub << 8;
#pragma unroll 2
    for (int i = 0; i < 256; i += 4){
        f32x4 cx = *(const f32x4*)&sx[jb + i];
        f32x4 cy = *(const f32x4*)&sy[jb + i];
        f32x4 cz = *(const f32x4*)&sz[jb + i];
#pragma unroll
        for (int u = 0; u < 4; ++u){
            int j = jb + i + u;
            float dxA = ax - cx[u], dyA = ay - cy[u], dzA = az - cz[u];
            float dA = fmaf(dxA, dxA, fmaf(dyA, dyA, dzA * dzA));
            float dxB = bx - cx[u], dyB = by - cy[u], dzB = bz - cz[u];
            float dB = fmaf(dxB, dxB, fmaf(dyB, dyB, dzB * dzB));
            // branchless sorted-3 insert (strict <, ascending-index scan => top_k tie semantics)
            {
                bool c2 = dA < A2, c1 = dA < A1, c0 = dA < A0;
                A2  = c1 ? A1  : (c2 ? dA : A2);
                Ai2 = c1 ? Ai1 : (c2 ? j  : Ai2);
                A1  = c0 ? A0  : (c1 ? dA : A1);
                Ai1 = c0 ? Ai0 : (c1 ? j  : Ai1);
                A0  = c0 ? dA  : A0;
                Ai0 = c0 ? j   : Ai0;
            }
            {
                bool c2 = dB < B2, c1 = dB < B1, c0 = dB < B0;
                B2  = c1 ? B1  : (c2 ? dB : B2);
                Bi2 = c1 ? Bi1 : (c2 ? j  : Bi2);
                B1  = c0 ? B0  : (c1 ? dB : B1);
                Bi1 = c0 ? Bi0 : (c1 ? j  : Bi1);
                B0  = c0 ? dB  : B0;
                Bi0 = c0 ? j   : Bi0;
            }
        }
    }
    int c = sub * 3;
    sd[pp][c] = A0; sd[pp][c+1] = A1; sd[pp][c+2] = A2;
    si[pp][c] = Ai0; si[pp][c+1] = Ai1; si[pp][c+2] = Ai2;
    sd[pp+32][c] = B0; sd[pp+32][c+1] = B1; sd[pp+32][c+2] = B2;
    si[pp+32][c] = Bi0; si[pp+32][c+1] = Bi1; si[pp+32][c+2] = Bi2;
    __syncthreads();
    if (threadIdx.x < 64){
        int lp = threadIdx.x;
        float d0 = 1e30f, d1 = 1e30f, d2 = 1e30f;
        int i0 = 0, i1 = 0, i2 = 0;
#pragma unroll
        for (int k = 0; k < 24; ++k){
            float d = sd[lp][k]; int j = si[lp][k];
            bool c2 = d < d2, c1 = d < d1, c0 = d < d0;
            d2 = c1 ? d1 : (c2 ? d : d2);
            i2 = c1 ? i1 : (c2 ? j : i2);
            d1 = c0 ? d0 : (c1 ? d : d1);
            i1 = c0 ? i0 : (c1 ? j : i1);
            d0 = c0 ? d  : d0;
            i0 = c0 ? j  : i0;
        }
        float w0 = 1.f / fmaxf(sqrtf(d0), 1e-8f);
        float w1 = 1.f / fmaxf(sqrtf(d1), 1e-8f);
        float w2 = 1.f / fmaxf(sqrtf(d2), 1e-8f);
        float inv = 1.f / (w0 + w1 + w2);
        int n = n0 + lp;
        size_t pbase = ((size_t)b * 8192 + n) * 3;
        ow[pbase + 0] = w0 * inv; ow[pbase + 1] = w1 * inv; ow[pbase + 2] = w2 * inv;
        oi[pbase + 0] = i0;       oi[pbase + 1] = i1;       oi[pbase + 2] = i2;
    }
}

// ---------------- feats2 (B,C2,N2) f32 -> f2t (B,N2,C2) bf16 ----------------
__global__ __launch_bounds__(256) void transpose_f2_kernel(const float* __restrict__ f2, unsigned short* __restrict__ f2t){
    __shared__ float tile[32][33];
    int b = blockIdx.z, c0 = blockIdx.y * 32, n0 = blockIdx.x * 32;
    int tx = threadIdx.x, ty = threadIdx.y;
    for (int i = 0; i < 32; i += 8)
        tile[ty + i][tx] = f2[((size_t)b * 256 + c0 + ty + i) * 2048 + n0 + tx];
    __syncthreads();
    for (int i = 0; i < 32; i += 8)
        f2t[((size_t)b * 2048 + n0 + ty + i) * 256 + c0 + tx] = f2bf(tile[tx][ty + i]);
}

// ---------------- interp: X[p][0..255] = sum_k w_k * f2t[b][idx_k][:] ----------------
// 2048 blocks x 256 threads; 32 points/block, 8 threads/point, 4x uint4 (8 bf16) per thread.
__global__ __launch_bounds__(256) void interp_kernel(const int* __restrict__ ki, const float* __restrict__ kw,
                                                     const unsigned short* __restrict__ f2t, unsigned short* __restrict__ X){
    int t = threadIdx.x;
    int p = blockIdx.x * 32 + (t >> 3);
    int q = t & 7;
    int b = p >> 13;
    const int*   ip = ki + (size_t)p * 3;
    const float* wp = kw + (size_t)p * 3;
    int i0 = ip[0], i1 = ip[1], i2 = ip[2];
    float w0 = wp[0], w1 = wp[1], w2 = wp[2];
    const uint4* F0 = (const uint4*)(f2t + ((size_t)b * 2048 + i0) * 256);
    const uint4* F1 = (const uint4*)(f2t + ((size_t)b * 2048 + i1) * 256);
    const uint4* F2 = (const uint4*)(f2t + ((size_t)b * 2048 + i2) * 256);
    uint4* Xp = (uint4*)(X + (size_t)p * 384);
#pragma unroll
    for (int s = 0; s < 4; ++s){
        int ch = q + s * 8;                  // uint4 index within the 256-ch row (0..31)
        uint4 a = F0[ch], c = F1[ch], d = F2[ch];
        uint4 r;
        unsigned* ap = (unsigned*)&a; unsigned* cp = (unsigned*)&c;
        unsigned* dp = (unsigned*)&d; unsigned* rp = (unsigned*)&r;
#pragma unroll
        for (int u = 0; u < 4; ++u){
            float lo = w0 * bf2f((unsigned short)(ap[u] & 0xffff))
                     + w1 * bf2f((unsigned short)(cp[u] & 0xffff))
                     + w2 * bf2f((unsigned short)(dp[u] & 0xffff));
            float hi = w0 * bf2f((unsigned short)(ap[u] >> 16))
                     + w1 * bf2f((unsigned short)(cp[u] >> 16))
                     + w2 * bf2f((unsigned short)(dp[u] >> 16));
            rp[u] = (unsigned)f2bf(lo) | ((unsigned)f2bf(hi) << 16);
        }
        Xp[ch] = r;
    }
}

// ---------------- feats1 (B,C1,N1) f32 -> X[p][256+c] bf16 ----------------
__global__ __launch_bounds__(256) void transpose_f1_kernel(const float* __restrict__ f1, unsigned short* __restrict__ X){
    __shared__ float tile[32][33];
    int b = blockIdx.z, c0 = blockIdx.y * 32, n0 = blockIdx.x * 32;
    int tx = threadIdx.x, ty = threadIdx.y;
    for (int i = 0; i < 32; i += 8)
        tile[ty + i][tx] = f1[((size_t)b * 128 + c0 + ty + i) * 8192 + n0 + tx];
    __syncthreads();
    for (int i = 0; i < 32; i += 8)
        X[((size_t)b * 8192 + n0 + ty + i) * 384 + 256 + c0 + tx] = f2bf(tile[tx][ty + i]);
}

// ---------------- bf16 MFMA GEMM: C[m][n] = sum_k A[m][k] * Bt[n][k] + bias[n] ----------------
template<int KT, bool OBF>
__global__ __launch_bounds__(256) void gemm_bt(const unsigned short* __restrict__ A, const unsigned short* __restrict__ Bt,
                                               const float* __restrict__ bias, void* __restrict__ Cout,
                                               float* __restrict__ gsum, float* __restrict__ gsq, int Ncols){
    __shared__ unsigned short As[128 * 32];
    __shared__ unsigned short Bs[128 * 32];
    __shared__ float sLs[128], sLq[128];
    int tid = threadIdx.x;
    if (tid < 128){ sLs[tid] = 0.f; sLq[tid] = 0.f; }
    int m0 = blockIdx.x * 128;
    int n0 = blockIdx.y * 128;
    int lane = tid & 63, wid = tid >> 6;
    int m_w = (wid >> 1) * 64, n_w = (wid & 1) * 64;
    f32x4 acc[4][4] = {};

    int srow = tid >> 2, schunk = tid & 3;
    const char* Ab = (const char*)A + ((size_t)(m0 + srow) * KT + schunk * 8) * 2;
    const char* Bb = (const char*)Bt + ((size_t)(n0 + srow) * KT + schunk * 8) * 2;
    char* Asl = (char*)As + tid * 16;
    char* Bsl = (char*)Bs + tid * 16;
    const size_t rstep = (size_t)64 * KT * 2;

    int lr = lane & 15, lq = lane >> 4;
    for (int kt = 0; kt < KT / 32; ++kt){
        size_t koff = (size_t)kt * 64;
        GLDS(Ab + koff, Asl);
        GLDS(Ab + koff + rstep, Asl + 4096);
        GLDS(Bb + koff, Bsl);
        GLDS(Bb + koff + rstep, Bsl + 4096);
        __syncthreads();
        short8 af[4], bfr[4];
#pragma unroll
        for (int mf = 0; mf < 4; ++mf)
            af[mf] = *(const short8*)(As + (m_w + mf * 16 + lr) * 32 + lq * 8);
#pragma unroll
        for (int nf = 0; nf < 4; ++nf)
            bfr[nf] = *(const short8*)(Bs + (n_w + nf * 16 + lr) * 32 + lq * 8);
#pragma unroll
        for (int mf = 0; mf < 4; ++mf)
#pragma unroll
            for (int nf = 0; nf < 4; ++nf)
                acc[mf][nf] = __builtin_amdgcn_mfma_f32_16x16x32_bf16(af[mf], bfr[nf], acc[mf][nf], 0, 0, 0);
        __syncthreads();
    }

    // epilogue: bias, store, BN stats
#pragma unroll
    for (int nf = 0; nf < 4; ++nf){
        int cl = n_w + nf * 16 + lr;
        int gc = n0 + cl;
        float bv = bias[gc];
        float ps = 0.f, pq = 0.f;
#pragma unroll
        for (int mf = 0; mf < 4; ++mf){
            int grow = m0 + m_w + mf * 16 + lq * 4;
#pragma unroll
            for (int r = 0; r < 4; ++r){
                float v = acc[mf][nf][r] + bv;
                size_t off = (size_t)(grow + r) * Ncols + gc;
                if (OBF) ((unsigned short*)Cout)[off] = f2bf(v);
                else     ((float*)Cout)[off] = v;
                ps += v; pq += v * v;
            }
        }
        ps += __shfl_xor(ps, 16); ps += __shfl_xor(ps, 32);
        pq += __shfl_xor(pq, 16); pq += __shfl_xor(pq, 32);
        if (lq == 0){ atomicAdd(&sLs[cl], ps); atomicAdd(&sLq[cl], pq); }
    }
    __syncthreads();
    if (tid < 128){
        atomicAdd(&gsum[n0 + tid], sLs[tid]);
        atomicAdd(&gsq[n0 + tid],  sLq[tid]);
    }
}

// ---------------- BN+ReLU in place on h1 (point-major, C=256, bf16) ----------------
__global__ __launch_bounds__(256) void bn_relu_bf16(unsigned short* __restrict__ h, const float* __restrict__ gsum,
                                                    const float* __restrict__ gsq, const float* __restrict__ gamma,
                                                    const float* __restrict__ beta){
    const float inv = 1.0f / 65536.0f;
    size_t total2 = (size_t)65536 * 128;  // ushort2 units
    unsigned* hp = (unsigned*)h;
    for (size_t i = (size_t)blockIdx.x * blockDim.x + threadIdx.x; i < total2; i += (size_t)gridDim.x * blockDim.x){
        int c0 = (int)((i * 2) & 255);
        unsigned v = hp[i];
        float x0 = bf2f((unsigned short)(v & 0xffff));
        float x1 = bf2f((unsigned short)(v >> 16));
        float m0 = gsum[c0] * inv,     m1 = gsum[c0 + 1] * inv;
        float va0 = gsq[c0] * inv - m0 * m0, va1 = gsq[c0 + 1] * inv - m1 * m1;
        float rs0 = rsqrtf(va0 + 1e-5f), rs1 = rsqrtf(va1 + 1e-5f);
        float y0 = fmaxf((x0 - m0) * rs0 * gamma[c0] + beta[c0], 0.f);
        float y1 = fmaxf((x1 - m1) * rs1 * gamma[c0 + 1] + beta[c0 + 1], 0.f);
        hp[i] = (unsigned)f2bf(y0) | ((unsigned)f2bf(y1) << 16);
    }
}

// ---------------- BN+ReLU on h2 + transpose (p,o)->(b,o,n) f32 out ----------------
__global__ __launch_bounds__(256) void bn2_transpose_kernel(const float* __restrict__ h2, const float* __restrict__ gsum,
                                                            const float* __restrict__ gsq, const float* __restrict__ g2,
                                                            const float* __restrict__ be2, float* __restrict__ out){
    __shared__ float tile[32][33];
    const float inv = 1.0f / 65536.0f;
    int b = blockIdx.z, o0 = blockIdx.y * 32, n0 = blockIdx.x * 32;
    int tx = threadIdx.x, ty = threadIdx.y;
    for (int i = 0; i < 32; i += 8)
        tile[ty + i][tx] = h2[((size_t)b * 8192 + n0 + ty + i) * 128 + o0 + tx];
    __syncthreads();
    for (int i = 0; i < 32; i += 8){
        int ch = o0 + ty + i;
        float m = gsum[ch] * inv;
        float va = gsq[ch] * inv - m * m;
        float rs = rsqrtf(va + 1e-5f);
        float sc = g2[ch] * rs, sh = be2[ch] - m * sc;
        float v = fmaxf(tile[tx][ty + i] * sc + sh, 0.f);
        out[((size_t)b * 128 + ch) * 8192 + n0 + tx] = v;
    }
}

extern "C" void kernel_launch(void* const* d_in, const int* in_sizes, int n_in,
                              void* d_out, int out_size, void* d_ws, size_t ws_size,
                              hipStream_t stream){
    const float* xyz1   = (const float*)d_in[0];
    const float* xyz2   = (const float*)d_in[1];
    const float* feats1 = (const float*)d_in[2];
    const float* feats2 = (const float*)d_in[3];
    const float* W1  = (const float*)d_in[4];
    const float* b1  = (const float*)d_in[5];
    const float* g1  = (const float*)d_in[6];
    const float* be1 = (const float*)d_in[7];
    const float* W2  = (const float*)d_in[8];
    const float* b2  = (const float*)d_in[9];
    const float* g2  = (const float*)d_in[10];
    const float* be2 = (const float*)d_in[11];
    float* out = (float*)d_out;

    char* p = (char*)d_ws;
    auto take = [&](size_t bytes) -> char* {
        char* r = p; p += (bytes + 255) & ~(size_t)255; return r;
    };
    unsigned short* W1c = (unsigned short*)take((size_t)98304 * 2);
    unsigned short* W2c = (unsigned short*)take((size_t)32768 * 2);
    int*   ki    = (int*)take((size_t)65536 * 3 * 4);
    float* kw    = (float*)take((size_t)65536 * 3 * 4);
    float* stats = (float*)take(768 * 4);
    unsigned short* f2t = (unsigned short*)take((size_t)8 * 2048 * 256 * 2);
    unsigned short* X   = (unsigned short*)take((size_t)65536 * 384 * 2);
    unsigned short* h1  = (unsigned short*)take((size_t)65536 * 256 * 2);
    float* h2 = (float*)X;  // X dead after gemm1; reuse for h2

    float* s1 = stats, *q1 = stats + 256, *s2 = stats + 512, *q2 = stats + 640;

    init_kernel<<<dim3(384), 256, 0, stream>>>(W1, W2, W1c, W2c, stats);
    knn_kernel<<<dim3(1024), 256, 0, stream>>>(xyz1, xyz2, ki, kw);
    transpose_f2_kernel<<<dim3(64, 8, 8), dim3(32, 8), 0, stream>>>(feats2, f2t);
    interp_kernel<<<dim3(2048), 256, 0, stream>>>(ki, kw, f2t, X);
    transpose_f1_kernel<<<dim3(256, 4, 8), dim3(32, 8), 0, stream>>>(feats1, X);
    gemm_bt<384, true><<<dim3(512, 2), 256, 0, stream>>>(X, W1c, b1, h1, s1, q1, 256);
    bn_relu_bf16<<<dim3(2048), 256, 0, stream>>>(h1, s1, q1, g1, be1);
    gemm_bt<256, false><<<dim3(512, 1), 256, 0, stream>>>(h1, W2c, b2, h2, s2, q2, 128);
    bn2_transpose_kernel<<<dim3(256, 4, 8), dim3(32, 8), 0, stream>>>(h2, s2, q2, g2, be2, out);
}

// Round 5
// 258.662 us; speedup vs baseline: 1.1627x; 1.1627x over previous
//
#include <hip/hip_runtime.h>

typedef __attribute__((ext_vector_type(8))) short short8;
typedef __attribute__((ext_vector_type(4))) float f32x4;

#define GLDS(gp, lp) __builtin_amdgcn_global_load_lds( \
    (const __attribute__((address_space(1))) void*)(gp), \
    (__attribute__((address_space(3))) void*)(lp), 16, 0, 0)

__device__ __forceinline__ unsigned short f2bf(float f){
    unsigned u = __float_as_uint(f);
    unsigned r = (u + 0x7fffu + ((u >> 16) & 1u)) >> 16;
    return (unsigned short)r;
}
__device__ __forceinline__ float bf2f(unsigned short s){
    return __uint_as_float(((unsigned)s) << 16);
}

// ---------------- init: cast weights to bf16 + zero stats ----------------
__global__ __launch_bounds__(256) void init_kernel(const float* __restrict__ W1, const float* __restrict__ W2,
                                                   unsigned short* __restrict__ W1c, unsigned short* __restrict__ W2c,
                                                   float* __restrict__ stats){
    int i = blockIdx.x * 256 + threadIdx.x;
    if (i < 98304) W1c[i] = f2bf(W1[i]);
    if (i < 32768) W2c[i] = f2bf(W2[i]);
    if (i < 768) stats[i] = 0.f;
}

// ---------------- KNN (3-NN) — round-2 proven version (branchy insert, 61us) ----------------
__global__ __launch_bounds__(256) void knn_kernel(const float* __restrict__ xyz1, const float* __restrict__ xyz2,
                                                  int* __restrict__ oi, float* __restrict__ ow){
    __shared__ float sx[2048], sy[2048], sz[2048];
    __shared__ float sd[64][25];
    __shared__ int   si[64][25];
    int blk = blockIdx.x;
    int b  = blk >> 7;
    int n0 = (blk & 127) << 6;
    const float* p2 = xyz2 + (size_t)b * 2048 * 3;
    for (int j = threadIdx.x; j < 2048; j += 256){
        sx[j] = p2[j*3+0]; sy[j] = p2[j*3+1]; sz[j] = p2[j*3+2];
    }
    __syncthreads();
    int pp = threadIdx.x & 31, sub = threadIdx.x >> 5;
    int pA = n0 + pp;
    const float* qa = xyz1 + ((size_t)b * 8192 + pA) * 3;
    float ax = qa[0], ay = qa[1], az = qa[2];
    float bx = qa[96], by = qa[97], bz = qa[98];   // point pA+32
    float A0 = 1e30f, A1 = 1e30f, A2 = 1e30f; int Ai0 = 0, Ai1 = 0, Ai2 = 0;
    float B0 = 1e30f, B1 = 1e30f, B2 = 1e30f; int Bi0 = 0, Bi1 = 0, Bi2 = 0;
    int jb = sub << 8;
#pragma unroll 2
    for (int i = 0; i < 256; i += 4){
        f32x4 cx = *(const f32x4*)&sx[jb + i];
        f32x4 cy = *(const f32x4*)&sy[jb + i];
        f32x4 cz = *(const f32x4*)&sz[jb + i];
#pragma unroll
        for (int u = 0; u < 4; ++u){
            int j = jb + i + u;
            float dxA = ax - cx[u], dyA = ay - cy[u], dzA = az - cz[u];
            float dA = fmaf(dxA, dxA, fmaf(dyA, dyA, dzA * dzA));
            float dxB = bx - cx[u], dyB = by - cy[u], dzB = bz - cz[u];
            float dB = fmaf(dxB, dxB, fmaf(dyB, dyB, dzB * dzB));
            if (dA < A2){
                if (dA < A1){
                    A2 = A1; Ai2 = Ai1;
                    if (dA < A0){ A1 = A0; Ai1 = Ai0; A0 = dA; Ai0 = j; }
                    else        { A1 = dA; Ai1 = j; }
                } else { A2 = dA; Ai2 = j; }
            }
            if (dB < B2){
                if (dB < B1){
                    B2 = B1; Bi2 = Bi1;
                    if (dB < B0){ B1 = B0; Bi1 = Bi0; B0 = dB; Bi0 = j; }
                    else        { B1 = dB; Bi1 = j; }
                } else { B2 = dB; Bi2 = j; }
            }
        }
    }
    int c = sub * 3;
    sd[pp][c] = A0; sd[pp][c+1] = A1; sd[pp][c+2] = A2;
    si[pp][c] = Ai0; si[pp][c+1] = Ai1; si[pp][c+2] = Ai2;
    sd[pp+32][c] = B0; sd[pp+32][c+1] = B1; sd[pp+32][c+2] = B2;
    si[pp+32][c] = Bi0; si[pp+32][c+1] = Bi1; si[pp+32][c+2] = Bi2;
    __syncthreads();
    if (threadIdx.x < 64){
        int lp = threadIdx.x;
        float d0 = 1e30f, d1 = 1e30f, d2 = 1e30f;
        int i0 = 0, i1 = 0, i2 = 0;
#pragma unroll
        for (int k = 0; k < 24; ++k){
            float d = sd[lp][k]; int j = si[lp][k];
            if (d < d2){
                if (d < d1){
                    d2 = d1; i2 = i1;
                    if (d < d0){ d1 = d0; i1 = i0; d0 = d; i0 = j; }
                    else        { d1 = d;  i1 = j; }
                } else { d2 = d; i2 = j; }
            }
        }
        float w0 = 1.f / fmaxf(sqrtf(d0), 1e-8f);
        float w1 = 1.f / fmaxf(sqrtf(d1), 1e-8f);
        float w2 = 1.f / fmaxf(sqrtf(d2), 1e-8f);
        float inv = 1.f / (w0 + w1 + w2);
        int n = n0 + lp;
        size_t pbase = ((size_t)b * 8192 + n) * 3;
        ow[pbase + 0] = w0 * inv; ow[pbase + 1] = w1 * inv; ow[pbase + 2] = w2 * inv;
        oi[pbase + 0] = i0;       oi[pbase + 1] = i1;       oi[pbase + 2] = i2;
    }
}

// ---------------- feats2 (B,C2,N2) f32 -> f2t (B,N2,C2) bf16 ----------------
__global__ __launch_bounds__(256) void transpose_f2_kernel(const float* __restrict__ f2, unsigned short* __restrict__ f2t){
    __shared__ float tile[32][33];
    int b = blockIdx.z, c0 = blockIdx.y * 32, n0 = blockIdx.x * 32;
    int tx = threadIdx.x, ty = threadIdx.y;
    for (int i = 0; i < 32; i += 8)
        tile[ty + i][tx] = f2[((size_t)b * 256 + c0 + ty + i) * 2048 + n0 + tx];
    __syncthreads();
    for (int i = 0; i < 32; i += 8)
        f2t[((size_t)b * 2048 + n0 + ty + i) * 256 + c0 + tx] = f2bf(tile[tx][ty + i]);
}

// ---------------- feats1 (B,C1,N1) f32 -> f1t[p][128] bf16 (compact) ----------------
__global__ __launch_bounds__(256) void transpose_f1_kernel(const float* __restrict__ f1, unsigned short* __restrict__ f1t){
    __shared__ float tile[32][33];
    int b = blockIdx.z, c0 = blockIdx.y * 32, n0 = blockIdx.x * 32;
    int tx = threadIdx.x, ty = threadIdx.y;
    for (int i = 0; i < 32; i += 8)
        tile[ty + i][tx] = f1[((size_t)b * 128 + c0 + ty + i) * 8192 + n0 + tx];
    __syncthreads();
    for (int i = 0; i < 32; i += 8)
        f1t[((size_t)b * 8192 + n0 + ty + i) * 128 + c0 + tx] = f2bf(tile[tx][ty + i]);
}

// ---------------- GEMM1 fused: A = [interp(f2t) | f1t] built in LDS; B = W1c ----------------
// grid 512 blocks; M-tile 128 points, N = 256 (full); 4 waves, wave tile 64x128.
__global__ __launch_bounds__(256, 2) void gemm1_fused(const unsigned short* __restrict__ f2t,
                                                      const unsigned short* __restrict__ f1t,
                                                      const int* __restrict__ ki, const float* __restrict__ kw,
                                                      const unsigned short* __restrict__ W1c,
                                                      const float* __restrict__ bias,
                                                      unsigned short* __restrict__ h1,
                                                      float* __restrict__ gsum, float* __restrict__ gsq){
    __shared__ unsigned short As[128 * 40];   // padded stride 40 (80B, 16B-aligned rows)
    __shared__ unsigned short Bs[256 * 32];
    __shared__ int   sIdx[384];
    __shared__ float sW[384];
    __shared__ float sLs[256], sLq[256];
    int tid = threadIdx.x;
    int m0 = blockIdx.x << 7;
    int b  = blockIdx.x >> 6;
    for (int i = tid; i < 384; i += 256){ sIdx[i] = ki[(size_t)m0 * 3 + i]; sW[i] = kw[(size_t)m0 * 3 + i]; }
    sLs[tid] = 0.f; sLq[tid] = 0.f;
    __syncthreads();

    int pt = tid >> 1, hh = tid & 1;
    int i0 = sIdx[pt*3], i1 = sIdx[pt*3+1], i2 = sIdx[pt*3+2];
    float w0 = sW[pt*3], w1 = sW[pt*3+1], w2 = sW[pt*3+2];
    const unsigned short* r0 = f2t + (((size_t)b * 2048 + i0) << 8);
    const unsigned short* r1 = f2t + (((size_t)b * 2048 + i1) << 8);
    const unsigned short* r2 = f2t + (((size_t)b * 2048 + i2) << 8);
    const unsigned short* f1row = f1t + ((size_t)(m0 + pt) << 7);
    unsigned short* awp = As + pt * 40 + hh * 16;

    int srow = tid >> 2, schunk = tid & 3;
    const char* Bb = (const char*)W1c + ((size_t)srow * 384 + schunk * 8) * 2;
    char* Bsl = (char*)Bs + tid * 16;

    int lane = tid & 63, wid = tid >> 6;
    int m_w = (wid >> 1) * 64, n_w = (wid & 1) * 128;
    int lr = lane & 15, lq = lane >> 4;
    f32x4 acc[4][8] = {};

    for (int kt = 0; kt < 12; ++kt){
        // B staging: 256 rows x 32 shorts
        size_t ko = (size_t)kt * 64;
        GLDS(Bb + ko,                 Bsl);
        GLDS(Bb + ko + (size_t)49152, Bsl + 4096);
        GLDS(Bb + ko + (size_t)98304, Bsl + 8192);
        GLDS(Bb + ko + (size_t)147456, Bsl + 12288);
        // A staging (reg -> LDS)
        if (kt < 8){
            int cb = kt * 32 + hh * 16;
            uint4 a0 = *(const uint4*)(r0 + cb);
            uint4 a1 = *(const uint4*)(r0 + cb + 8);
            uint4 c0 = *(const uint4*)(r1 + cb);
            uint4 c1 = *(const uint4*)(r1 + cb + 8);
            uint4 d0 = *(const uint4*)(r2 + cb);
            uint4 d1 = *(const uint4*)(r2 + cb + 8);
            uint4 o0, o1;
            const unsigned* ap = (const unsigned*)&a0; const unsigned* cp = (const unsigned*)&c0;
            const unsigned* dp = (const unsigned*)&d0; unsigned* op = (unsigned*)&o0;
#pragma unroll
            for (int u = 0; u < 4; ++u){
                float lo = w0 * bf2f((unsigned short)(ap[u] & 0xffff))
                         + w1 * bf2f((unsigned short)(cp[u] & 0xffff))
                         + w2 * bf2f((unsigned short)(dp[u] & 0xffff));
                float hi = w0 * bf2f((unsigned short)(ap[u] >> 16))
                         + w1 * bf2f((unsigned short)(cp[u] >> 16))
                         + w2 * bf2f((unsigned short)(dp[u] >> 16));
                op[u] = (unsigned)f2bf(lo) | ((unsigned)f2bf(hi) << 16);
            }
            ap = (const unsigned*)&a1; cp = (const unsigned*)&c1;
            dp = (const unsigned*)&d1; op = (unsigned*)&o1;
#pragma unroll
            for (int u = 0; u < 4; ++u){
                float lo = w0 * bf2f((unsigned short)(ap[u] & 0xffff))
                         + w1 * bf2f((unsigned short)(cp[u] & 0xffff))
                         + w2 * bf2f((unsigned short)(dp[u] & 0xffff));
                float hi = w0 * bf2f((unsigned short)(ap[u] >> 16))
                         + w1 * bf2f((unsigned short)(cp[u] >> 16))
                         + w2 * bf2f((unsigned short)(dp[u] >> 16));
                op[u] = (unsigned)f2bf(lo) | ((unsigned)f2bf(hi) << 16);
            }
            *(uint4*)awp = o0;
            *(uint4*)(awp + 8) = o1;
        } else {
            int cb = (kt - 8) * 32 + hh * 16;
            uint4 v0 = *(const uint4*)(f1row + cb);
            uint4 v1 = *(const uint4*)(f1row + cb + 8);
            *(uint4*)awp = v0;
            *(uint4*)(awp + 8) = v1;
        }
        __syncthreads();
        short8 af[4], bfr[8];
#pragma unroll
        for (int mf = 0; mf < 4; ++mf)
            af[mf] = *(const short8*)(As + (m_w + mf * 16 + lr) * 40 + lq * 8);
#pragma unroll
        for (int nf = 0; nf < 8; ++nf)
            bfr[nf] = *(const short8*)(Bs + (n_w + nf * 16 + lr) * 32 + lq * 8);
#pragma unroll
        for (int mf = 0; mf < 4; ++mf)
#pragma unroll
            for (int nf = 0; nf < 8; ++nf)
                acc[mf][nf] = __builtin_amdgcn_mfma_f32_16x16x32_bf16(af[mf], bfr[nf], acc[mf][nf], 0, 0, 0);
        __syncthreads();
    }

    // epilogue: bias, bf16 store, BN stats
#pragma unroll
    for (int nf = 0; nf < 8; ++nf){
        int gc = n_w + nf * 16 + lr;
        float bv = bias[gc];
        float ps = 0.f, pq = 0.f;
#pragma unroll
        for (int mf = 0; mf < 4; ++mf){
            int grow = m0 + m_w + mf * 16 + lq * 4;
#pragma unroll
            for (int r = 0; r < 4; ++r){
                float v = acc[mf][nf][r] + bv;
                h1[(size_t)(grow + r) * 256 + gc] = f2bf(v);
                ps += v; pq += v * v;
            }
        }
        ps += __shfl_xor(ps, 16); ps += __shfl_xor(ps, 32);
        pq += __shfl_xor(pq, 16); pq += __shfl_xor(pq, 32);
        if (lq == 0){ atomicAdd(&sLs[gc], ps); atomicAdd(&sLq[gc], pq); }
    }
    __syncthreads();
    atomicAdd(&gsum[tid], sLs[tid]);
    atomicAdd(&gsq[tid],  sLq[tid]);
}

// ---------------- BN1 scale/shift prep ----------------
__global__ void bnprep_kernel(const float* __restrict__ s1, const float* __restrict__ q1,
                              const float* __restrict__ g1, const float* __restrict__ be1,
                              float* __restrict__ sc, float* __restrict__ sh){
    int c = threadIdx.x;
    const float inv = 1.0f / 65536.0f;
    float m = s1[c] * inv;
    float v = q1[c] * inv - m * m;
    float rs = rsqrtf(v + 1e-5f);
    float s = g1[c] * rs;
    sc[c] = s; sh[c] = be1[c] - m * s;
}

// ---------------- GEMM2 fused: A = BN1+ReLU(h1) built in LDS; B = W2c ----------------
// grid 512 blocks; M-tile 128 points, N = 128; 4 waves, wave tile 64x64.
__global__ __launch_bounds__(256, 2) void gemm2_fused(const unsigned short* __restrict__ h1,
                                                      const unsigned short* __restrict__ W2c,
                                                      const float* __restrict__ bias,
                                                      const float* __restrict__ sc1, const float* __restrict__ sh1,
                                                      float* __restrict__ h2,
                                                      float* __restrict__ gsum, float* __restrict__ gsq){
    __shared__ unsigned short As[128 * 40];
    __shared__ unsigned short Bs[128 * 32];
    __shared__ float ssc[256], ssh[256];
    __shared__ float sLs[128], sLq[128];
    int tid = threadIdx.x;
    int m0 = blockIdx.x << 7;
    ssc[tid] = sc1[tid]; ssh[tid] = sh1[tid];
    if (tid < 128){ sLs[tid] = 0.f; sLq[tid] = 0.f; }
    __syncthreads();

    int pt = tid >> 1, hh = tid & 1;
    const unsigned short* hrow = h1 + ((size_t)(m0 + pt) << 8);
    unsigned short* awp = As + pt * 40 + hh * 16;

    int srow = tid >> 2, schunk = tid & 3;
    const char* Bb = (const char*)W2c + ((size_t)srow * 256 + schunk * 8) * 2;
    char* Bsl = (char*)Bs + tid * 16;

    int lane = tid & 63, wid = tid >> 6;
    int m_w = (wid >> 1) * 64, n_w = (wid & 1) * 64;
    int lr = lane & 15, lq = lane >> 4;
    f32x4 acc[4][4] = {};

    for (int kt = 0; kt < 8; ++kt){
        size_t ko = (size_t)kt * 64;
        GLDS(Bb + ko,                Bsl);
        GLDS(Bb + ko + (size_t)32768, Bsl + 4096);
        int cb = kt * 32 + hh * 16;
        uint4 v0 = *(const uint4*)(hrow + cb);
        uint4 v1 = *(const uint4*)(hrow + cb + 8);
        uint4 o0, o1;
        const unsigned* vp = (const unsigned*)&v0; unsigned* op = (unsigned*)&o0;
#pragma unroll
        for (int u = 0; u < 4; ++u){
            int cc = cb + 2 * u;
            float lo = fmaxf(bf2f((unsigned short)(vp[u] & 0xffff)) * ssc[cc]     + ssh[cc],     0.f);
            float hi = fmaxf(bf2f((unsigned short)(vp[u] >> 16))    * ssc[cc + 1] + ssh[cc + 1], 0.f);
            op[u] = (unsigned)f2bf(lo) | ((unsigned)f2bf(hi) << 16);
        }
        vp = (const unsigned*)&v1; op = (unsigned*)&o1;
#pragma unroll
        for (int u = 0; u < 4; ++u){
            int cc = cb + 8 + 2 * u;
            float lo = fmaxf(bf2f((unsigned short)(vp[u] & 0xffff)) * ssc[cc]     + ssh[cc],     0.f);
            float hi = fmaxf(bf2f((unsigned short)(vp[u] >> 16))    * ssc[cc + 1] + ssh[cc + 1], 0.f);
            op[u] = (unsigned)f2bf(lo) | ((unsigned)f2bf(hi) << 16);
        }
        *(uint4*)awp = o0;
        *(uint4*)(awp + 8) = o1;
        __syncthreads();
        short8 af[4], bfr[4];
#pragma unroll
        for (int mf = 0; mf < 4; ++mf)
            af[mf] = *(const short8*)(As + (m_w + mf * 16 + lr) * 40 + lq * 8);
#pragma unroll
        for (int nf = 0; nf < 4; ++nf)
            bfr[nf] = *(const short8*)(Bs + (n_w + nf * 16 + lr) * 32 + lq * 8);
#pragma unroll
        for (int mf = 0; mf < 4; ++mf)
#pragma unroll
            for (int nf = 0; nf < 4; ++nf)
                acc[mf][nf] = __builtin_amdgcn_mfma_f32_16x16x32_bf16(af[mf], bfr[nf], acc[mf][nf], 0, 0, 0);
        __syncthreads();
    }

#pragma unroll
    for (int nf = 0; nf < 4; ++nf){
        int gc = n_w + nf * 16 + lr;
        float bv = bias[gc];
        float ps = 0.f, pq = 0.f;
#pragma unroll
        for (int mf = 0; mf < 4; ++mf){
            int grow = m0 + m_w + mf * 16 + lq * 4;
#pragma unroll
            for (int r = 0; r < 4; ++r){
                float v = acc[mf][nf][r] + bv;
                h2[(size_t)(grow + r) * 128 + gc] = v;
                ps += v; pq += v * v;
            }
        }
        ps += __shfl_xor(ps, 16); ps += __shfl_xor(ps, 32);
        pq += __shfl_xor(pq, 16); pq += __shfl_xor(pq, 32);
        if (lq == 0){ atomicAdd(&sLs[gc], ps); atomicAdd(&sLq[gc], pq); }
    }
    __syncthreads();
    if (tid < 128){
        atomicAdd(&gsum[tid], sLs[tid]);
        atomicAdd(&gsq[tid],  sLq[tid]);
    }
}

// ---------------- BN+ReLU on h2 + transpose (p,o)->(b,o,n) f32 out ----------------
__global__ __launch_bounds__(256) void bn2_transpose_kernel(const float* __restrict__ h2, const float* __restrict__ gsum,
                                                            const float* __restrict__ gsq, const float* __restrict__ g2,
                                                            const float* __restrict__ be2, float* __restrict__ out){
    __shared__ float tile[32][33];
    const float inv = 1.0f / 65536.0f;
    int b = blockIdx.z, o0 = blockIdx.y * 32, n0 = blockIdx.x * 32;
    int tx = threadIdx.x, ty = threadIdx.y;
    for (int i = 0; i < 32; i += 8)
        tile[ty + i][tx] = h2[((size_t)b * 8192 + n0 + ty + i) * 128 + o0 + tx];
    __syncthreads();
    for (int i = 0; i < 32; i += 8){
        int ch = o0 + ty + i;
        float m = gsum[ch] * inv;
        float va = gsq[ch] * inv - m * m;
        float rs = rsqrtf(va + 1e-5f);
        float sc = g2[ch] * rs, sh = be2[ch] - m * sc;
        float v = fmaxf(tile[tx][ty + i] * sc + sh, 0.f);
        out[((size_t)b * 128 + ch) * 8192 + n0 + tx] = v;
    }
}

extern "C" void kernel_launch(void* const* d_in, const int* in_sizes, int n_in,
                              void* d_out, int out_size, void* d_ws, size_t ws_size,
                              hipStream_t stream){
    const float* xyz1   = (const float*)d_in[0];
    const float* xyz2   = (const float*)d_in[1];
    const float* feats1 = (const float*)d_in[2];
    const float* feats2 = (const float*)d_in[3];
    const float* W1  = (const float*)d_in[4];
    const float* b1  = (const float*)d_in[5];
    const float* g1  = (const float*)d_in[6];
    const float* be1 = (const float*)d_in[7];
    const float* W2  = (const float*)d_in[8];
    const float* b2  = (const float*)d_in[9];
    const float* g2  = (const float*)d_in[10];
    const float* be2 = (const float*)d_in[11];
    float* out = (float*)d_out;

    char* p = (char*)d_ws;
    auto take = [&](size_t bytes) -> char* {
        char* r = p; p += (bytes + 255) & ~(size_t)255; return r;
    };
    unsigned short* W1c = (unsigned short*)take((size_t)98304 * 2);
    unsigned short* W2c = (unsigned short*)take((size_t)32768 * 2);
    int*   ki    = (int*)take((size_t)65536 * 3 * 4);
    float* kw    = (float*)take((size_t)65536 * 3 * 4);
    float* stats = (float*)take(768 * 4);
    float* scsh  = (float*)take(512 * 4);
    unsigned short* f2t = (unsigned short*)take((size_t)8 * 2048 * 256 * 2);
    unsigned short* f1t = (unsigned short*)take((size_t)65536 * 128 * 2);
    unsigned short* h1  = (unsigned short*)take((size_t)65536 * 256 * 2);
    float* h2 = (float*)take((size_t)65536 * 128 * 4);

    float* s1 = stats, *q1 = stats + 256, *s2 = stats + 512, *q2 = stats + 640;
    float* sc1 = scsh, *sh1 = scsh + 256;

    init_kernel<<<dim3(384), 256, 0, stream>>>(W1, W2, W1c, W2c, stats);
    knn_kernel<<<dim3(1024), 256, 0, stream>>>(xyz1, xyz2, ki, kw);
    transpose_f2_kernel<<<dim3(64, 8, 8), dim3(32, 8), 0, stream>>>(feats2, f2t);
    transpose_f1_kernel<<<dim3(256, 4, 8), dim3(32, 8), 0, stream>>>(feats1, f1t);
    gemm1_fused<<<dim3(512), 256, 0, stream>>>(f2t, f1t, ki, kw, W1c, b1, h1, s1, q1);
    bnprep_kernel<<<dim3(1), 256, 0, stream>>>(s1, q1, g1, be1, sc1, sh1);
    gemm2_fused<<<dim3(512), 256, 0, stream>>>(h1, W2c, b2, sc1, sh1, h2, s2, q2);
    bn2_transpose_kernel<<<dim3(256, 4, 8), dim3(32, 8), 0, stream>>>(h2, s2, q2, g2, be2, out);
}